// Round 16
// baseline (393.492 us; speedup 1.0000x reference)
//
#include <hip/hip_runtime.h>
#include <hip/hip_bf16.h>

// MultiDilatelocalAttention, round 16: round 13 + T=4 multi-token attention.
// Each thread owns 4 consecutive tokens (one head): unique k/v columns per
// row-tap = 4+2*dil instead of 12 -> 1.46x fewer L3 bytes, no cross-thread
// sync. Head-major layout => dilation is compile-time per branch arm (static
// tap->col map, zero guard waste). GEMMs/conv = round 13 exact.

#define NTOK 50176
#define ROWQKV 1152
#define CDIM 384

typedef _Float16 half2v __attribute__((ext_vector_type(2)));
typedef _Float16 half8 __attribute__((ext_vector_type(8)));
typedef float floatx4 __attribute__((ext_vector_type(4)));

typedef __attribute__((address_space(1))) const unsigned int GU32;
typedef __attribute__((address_space(3))) unsigned int LU32;

// ---------------- fused fp32 -> fp16 conversion: x, w_qkv, w_proj ----------------
#define N_X4 (NTOK * CDIM / 4)
#define N_Q4 (ROWQKV * CDIM / 4)
#define N_P4 (CDIM * CDIM / 4)

__global__ __launch_bounds__(256) void conv_all(const float* __restrict__ x,
                                                const float* __restrict__ wq,
                                                const float* __restrict__ wp,
                                                _Float16* __restrict__ xh,
                                                _Float16* __restrict__ wqh,
                                                _Float16* __restrict__ wph) {
  const int total = N_X4 + N_Q4 + N_P4;
  int i = blockIdx.x * 256 + threadIdx.x;
  const int stride = gridDim.x * 256;
  for (; i < total; i += stride) {
    const float* src;
    _Float16* dst;
    int k;
    if (i < N_X4) { src = x; dst = xh; k = i; }
    else if (i < N_X4 + N_Q4) { src = wq; dst = wqh; k = i - N_X4; }
    else { src = wp; dst = wph; k = i - N_X4 - N_Q4; }
    float4 v = ((const float4*)src)[k];
    union { _Float16 h[4]; uint2 u; } o;
    o.h[0] = (_Float16)v.x; o.h[1] = (_Float16)v.y;
    o.h[2] = (_Float16)v.z; o.h[3] = (_Float16)v.w;
    ((uint2*)dst)[k] = o.u;
  }
}

// ---------------- f16 MFMA GEMM (round-8 exact): C = A * B^T, dbuf + vmcnt(4) ----------------
template <bool HALF_OUT>
__global__ __launch_bounds__(256) void gemm3(const _Float16* __restrict__ A,
                                             const _Float16* __restrict__ B,
                                             const float* __restrict__ bias,
                                             void* __restrict__ Cout,
                                             int N, int K) {
  __shared__ _Float16 Asl[2][128 * 32];
  __shared__ _Float16 Bsl[2][128 * 32];
  const int tid = threadIdx.x;
  const int lane = tid & 63;
  const int wv = tid >> 6;
  const int wr = wv >> 1, wc = wv & 1;

  const int nN = N >> 7;
  const int p = blockIdx.x;
  const int l = (p & 7) * (gridDim.x >> 3) + (p >> 3);
  const size_t row0 = (size_t)(l / nN) * 128;
  const int col0 = (l % nN) * 128;
  const int NT = K / 32;

  const int srow = tid >> 2;
  const int gslot = (tid & 3) ^ ((srow >> 1) & 3);
  const _Float16* Abase = A + (row0 + srow) * (size_t)K + gslot * 8;
  const _Float16* Bbase = B + ((size_t)(col0 + srow)) * (size_t)K + gslot * 8;
  char* AsB = (char*)Asl;
  char* BsB = (char*)Bsl;

  auto stage = [&](int k0, int buf) {
    __builtin_amdgcn_global_load_lds((GU32*)(Abase + k0),
                                     (LU32*)(AsB + buf * 8192 + tid * 16), 16, 0, 0);
    __builtin_amdgcn_global_load_lds((GU32*)(Abase + (size_t)64 * K + k0),
                                     (LU32*)(AsB + buf * 8192 + tid * 16 + 4096), 16, 0, 0);
    __builtin_amdgcn_global_load_lds((GU32*)(Bbase + k0),
                                     (LU32*)(BsB + buf * 8192 + tid * 16), 16, 0, 0);
    __builtin_amdgcn_global_load_lds((GU32*)(Bbase + (size_t)64 * K + k0),
                                     (LU32*)(BsB + buf * 8192 + tid * 16 + 4096), 16, 0, 0);
  };

  const int fr = lane & 15;
  const int fq = lane >> 4;
  const int rpos = (fq ^ ((fr >> 1) & 3)) * 8;

  floatx4 acc[4][4];
#pragma unroll
  for (int i = 0; i < 4; ++i)
#pragma unroll
    for (int j = 0; j < 4; ++j) acc[i][j] = (floatx4){0.f, 0.f, 0.f, 0.f};

  stage(0, 0);
  asm volatile("s_waitcnt vmcnt(0)" ::: "memory");
  __builtin_amdgcn_s_barrier();

  int cur = 0;
  for (int t = 0; t < NT; ++t) {
    if (t + 1 < NT) {
      stage((t + 1) * 32, cur ^ 1);
      asm volatile("s_waitcnt vmcnt(4)" ::: "memory");
    } else {
      asm volatile("s_waitcnt vmcnt(0)" ::: "memory");
    }
    __builtin_amdgcn_s_barrier();
    __builtin_amdgcn_sched_barrier(0);
    half8 af[4], bf[4];
#pragma unroll
    for (int f = 0; f < 4; ++f) {
      af[f] = *(const half8*)&Asl[cur][(wr * 64 + f * 16 + fr) * 32 + rpos];
      bf[f] = *(const half8*)&Bsl[cur][(wc * 64 + f * 16 + fr) * 32 + rpos];
    }
#pragma unroll
    for (int i = 0; i < 4; ++i)
#pragma unroll
      for (int j = 0; j < 4; ++j)
        acc[i][j] = __builtin_amdgcn_mfma_f32_16x16x32_f16(af[i], bf[j], acc[i][j], 0, 0, 0);
    __builtin_amdgcn_sched_barrier(0);
    __builtin_amdgcn_s_barrier();
    cur ^= 1;
  }

  const int crow = wr * 64 + (lane >> 4) * 4;
  const int ccol = wc * 64 + (lane & 15);
#pragma unroll
  for (int fm = 0; fm < 4; ++fm) {
#pragma unroll
    for (int fn = 0; fn < 4; ++fn) {
      const size_t r0 = (row0 + crow + fm * 16) * (size_t)N + col0 + ccol + fn * 16;
      if (HALF_OUT) {
        _Float16* Cc = (_Float16*)Cout;
#pragma unroll
        for (int j = 0; j < 4; ++j) Cc[r0 + (size_t)j * N] = (_Float16)acc[fm][fn][j];
      } else {
        float* Cc = (float*)Cout;
        const float bz = bias[col0 + ccol + fn * 16];
#pragma unroll
        for (int j = 0; j < 4; ++j) Cc[r0 + (size_t)j * N] = acc[fm][fn][j] + bz;
      }
    }
  }
}

// ---------------- T=4 multi-token attention ----------------
// Thread = (group of 4 consecutive tokens in x, head-in-branch). Columns
// c in [0, 4+2*DIL) at nx = x0-DIL+c; tap (dy, jx) of token di uses column
// c = di + jx*DIL (exactly one col per tap; OOB col -> zeros -> logit 0).
template <int DIL>
__device__ __forceinline__ void attn_body(const _Float16* __restrict__ qkv,
                                          _Float16* __restrict__ y,
                                          int group, int head) {
  const int bimg = group / 784;          // 784 = 56 rows * 14 xgroups
  const int rem = group - bimg * 784;
  const int yy = rem / 14;
  const int x0 = (rem % 14) * 4;
  const int cbase = (DIL - 1) * 128 + head * 32;
  const size_t base = (size_t)bimg * 3136;
  const float scale = 0.17677669529663687f;  // 1/sqrt(32)

  // q for the 4 tokens
  half2v qh[4][16];
#pragma unroll
  for (int i = 0; i < 4; ++i) {
    const _Float16* qp = qkv + (base + yy * 56 + x0 + i) * ROWQKV + cbase;
#pragma unroll
    for (int g = 0; g < 4; ++g)
      *(half8*)&qh[i][g * 4] = *(const half8*)(qp + g * 8);
  }

  constexpr int NC = 4 + 2 * DIL;
  float lg[4][9];

  // pass 1: logits (each tap assigned exactly once)
#pragma unroll
  for (int dy = 0; dy < 3; ++dy) {
    const int ny = yy + (dy - 1) * DIL;
    const bool rok = (unsigned)ny < 56u;
#pragma unroll
    for (int c = 0; c < NC; ++c) {
      const int nx = x0 - DIL + c;
      half2v kh[16];
      if (rok && (unsigned)nx < 56u) {
        const _Float16* kp = qkv + (base + ny * 56 + nx) * ROWQKV + 384 + cbase;
#pragma unroll
        for (int g = 0; g < 4; ++g)
          *(half8*)&kh[g * 4] = *(const half8*)(kp + g * 8);
      } else {
#pragma unroll
        for (int g = 0; g < 16; ++g) kh[g] = (half2v){(_Float16)0.f, (_Float16)0.f};
      }
#pragma unroll
      for (int jx = 0; jx < 3; ++jx) {
        const int di = c - jx * DIL;  // unroll-constant
        if (di >= 0 && di < 4) {
          float d = 0.f;
#pragma unroll
          for (int cc = 0; cc < 16; ++cc)
            d = __builtin_amdgcn_fdot2(qh[di][cc], kh[cc], d, false);
          lg[di][dy * 3 + jx] = d * scale;
        }
      }
    }
  }

  // softmax per token (same order as round 13)
  float rs[4];
#pragma unroll
  for (int i = 0; i < 4; ++i) {
    float m = lg[i][0];
#pragma unroll
    for (int j = 1; j < 9; ++j) m = fmaxf(m, lg[i][j]);
    float s = 0.f;
#pragma unroll
    for (int j = 0; j < 9; ++j) { lg[i][j] = expf(lg[i][j] - m); s += lg[i][j]; }
    rs[i] = 1.f / s;
  }

  // pass 2: PV (taps per token arrive in the same j order as round 13)
  float out[4][32];
#pragma unroll
  for (int i = 0; i < 4; ++i)
#pragma unroll
    for (int c = 0; c < 32; ++c) out[i][c] = 0.f;

#pragma unroll
  for (int dy = 0; dy < 3; ++dy) {
    const int ny = yy + (dy - 1) * DIL;
    const bool rok = (unsigned)ny < 56u;
#pragma unroll
    for (int c = 0; c < NC; ++c) {
      const int nx = x0 - DIL + c;
      half8 vh[4];
      if (rok && (unsigned)nx < 56u) {
        const _Float16* vp = qkv + (base + ny * 56 + nx) * ROWQKV + 768 + cbase;
#pragma unroll
        for (int g = 0; g < 4; ++g) vh[g] = *(const half8*)(vp + g * 8);
      } else {
#pragma unroll
        for (int g = 0; g < 4; ++g)
#pragma unroll
          for (int e = 0; e < 8; ++e) vh[g][e] = (_Float16)0.f;
      }
#pragma unroll
      for (int jx = 0; jx < 3; ++jx) {
        const int di = c - jx * DIL;
        if (di >= 0 && di < 4) {
          const float pw = lg[di][dy * 3 + jx];
#pragma unroll
          for (int g = 0; g < 4; ++g)
#pragma unroll
            for (int e = 0; e < 8; ++e)
              out[di][g * 8 + e] = fmaf(pw, (float)vh[g][e], out[di][g * 8 + e]);
        }
      }
    }
  }

  // write
#pragma unroll
  for (int i = 0; i < 4; ++i) {
    _Float16* yp = y + (base + yy * 56 + x0 + i) * (size_t)CDIM + cbase;
#pragma unroll
    for (int g = 0; g < 4; ++g) {
      half8 oh;
#pragma unroll
      for (int e = 0; e < 8; ++e) oh[e] = (_Float16)(out[i][g * 8 + e] * rs[i]);
      *(half8*)(yp + g * 8) = oh;
    }
  }
}

// Grid 588 = 3 branches x 196 blocks; bijective XCD remap (588 = 8*73 + 4).
__global__ __launch_bounds__(256) void attn_t4(const _Float16* __restrict__ qkv,
                                               _Float16* __restrict__ y) {
  const int p = blockIdx.x;
  const int xcd = p & 7, bi = p >> 3;
  const int l = (xcd < 4) ? xcd * 74 + bi : 296 + (xcd - 4) * 73 + bi;
  const int branch = l / 196;
  const int bb = l - branch * 196;
  const int u = bb * 256 + threadIdx.x;
  const int head = u & 3;
  const int group = u >> 2;
  if (branch == 0) attn_body<1>(qkv, y, group, head);
  else if (branch == 1) attn_body<2>(qkv, y, group, head);
  else attn_body<3>(qkv, y, group, head);
}

extern "C" void kernel_launch(void* const* d_in, const int* in_sizes, int n_in,
                              void* d_out, int out_size, void* d_ws, size_t ws_size,
                              hipStream_t stream) {
  const float* x = (const float*)d_in[0];       // [16,56,56,384]
  const float* w_qkv = (const float*)d_in[1];   // [1152,384]
  const float* w_proj = (const float*)d_in[2];  // [384,384]
  const float* b_proj = (const float*)d_in[3];  // [384]
  float* out = (float*)d_out;                   // [50176,384]

  _Float16* xh = (_Float16*)d_ws;                     // 50176*384
  _Float16* wqh = xh + (size_t)NTOK * CDIM;           // 1152*384
  _Float16* wph = wqh + (size_t)ROWQKV * CDIM;        // 384*384
  _Float16* qkvh = wph + (size_t)CDIM * CDIM;         // 50176*1152
  _Float16* yh = qkvh + (size_t)NTOK * ROWQKV;        // 50176*384

  conv_all<<<2048, 256, 0, stream>>>(x, w_qkv, w_proj, xh, wqh, wph);

  gemm3<true><<<(NTOK / 128) * (ROWQKV / 128), 256, 0, stream>>>(
      xh, wqh, nullptr, qkvh, ROWQKV, CDIM);

  attn_t4<<<588, 256, 0, stream>>>(qkvh, yh);

  gemm3<false><<<(NTOK / 128) * (CDIM / 128), 256, 0, stream>>>(
      yh, wph, b_proj, out, CDIM, CDIM);
}

// Round 17
// 197.267 us; speedup vs baseline: 1.9947x; 1.9947x over previous
//
#include <hip/hip_runtime.h>
#include <hip/hip_bf16.h>

// MultiDilatelocalAttention, round 17: round 13 + operand-swapped MFMA epilogue.
// mfma(bf, af, acc) gives lane-contiguous C columns (row=lane&15, cols=fq*4+j)
// -> 16 vector stores per thread (f16x4 / float4) instead of 64 scalar stores.
// Identical arithmetic; attacks the VMEM-issue bound. attn = round 13 exact.

#define NTOK 50176
#define ROWQKV 1152
#define CDIM 384

typedef _Float16 half2v __attribute__((ext_vector_type(2)));
typedef _Float16 half4 __attribute__((ext_vector_type(4)));
typedef _Float16 half8 __attribute__((ext_vector_type(8)));
typedef float floatx4 __attribute__((ext_vector_type(4)));

typedef __attribute__((address_space(1))) const unsigned int GU32;
typedef __attribute__((address_space(3))) unsigned int LU32;

// ---------------- fused fp32 -> fp16 conversion: x, w_qkv, w_proj ----------------
#define N_X4 (NTOK * CDIM / 4)
#define N_Q4 (ROWQKV * CDIM / 4)
#define N_P4 (CDIM * CDIM / 4)

__global__ __launch_bounds__(256) void conv_all(const float* __restrict__ x,
                                                const float* __restrict__ wq,
                                                const float* __restrict__ wp,
                                                _Float16* __restrict__ xh,
                                                _Float16* __restrict__ wqh,
                                                _Float16* __restrict__ wph) {
  const int total = N_X4 + N_Q4 + N_P4;
  int i = blockIdx.x * 256 + threadIdx.x;
  const int stride = gridDim.x * 256;
  for (; i < total; i += stride) {
    const float* src;
    _Float16* dst;
    int k;
    if (i < N_X4) { src = x; dst = xh; k = i; }
    else if (i < N_X4 + N_Q4) { src = wq; dst = wqh; k = i - N_X4; }
    else { src = wp; dst = wph; k = i - N_X4 - N_Q4; }
    float4 v = ((const float4*)src)[k];
    union { _Float16 h[4]; uint2 u; } o;
    o.h[0] = (_Float16)v.x; o.h[1] = (_Float16)v.y;
    o.h[2] = (_Float16)v.z; o.h[3] = (_Float16)v.w;
    ((uint2*)dst)[k] = o.u;
  }
}

// ---------------- f16 MFMA GEMM: C = A * B^T, dbuf + vmcnt(4), vector epilogue ----------------
// MFMA called as mfma(bf, af, acc): D-fragment holds C^T, so per lane
// C-row = wr*64 + fm*16 + (lane&15), C-cols = wc*64 + fn*16 + (lane>>4)*4 + j
// (j=0..3 contiguous) -> one 8B (f16) or 16B (f32+bias) store per fragment.
template <bool HALF_OUT>
__global__ __launch_bounds__(256) void gemm3(const _Float16* __restrict__ A,
                                             const _Float16* __restrict__ B,
                                             const float* __restrict__ bias,
                                             void* __restrict__ Cout,
                                             int N, int K) {
  __shared__ _Float16 Asl[2][128 * 32];
  __shared__ _Float16 Bsl[2][128 * 32];
  const int tid = threadIdx.x;
  const int lane = tid & 63;
  const int wv = tid >> 6;
  const int wr = wv >> 1, wc = wv & 1;

  const int nN = N >> 7;
  const int p = blockIdx.x;
  const int l = (p & 7) * (gridDim.x >> 3) + (p >> 3);
  const size_t row0 = (size_t)(l / nN) * 128;
  const int col0 = (l % nN) * 128;
  const int NT = K / 32;

  const int srow = tid >> 2;
  const int gslot = (tid & 3) ^ ((srow >> 1) & 3);
  const _Float16* Abase = A + (row0 + srow) * (size_t)K + gslot * 8;
  const _Float16* Bbase = B + ((size_t)(col0 + srow)) * (size_t)K + gslot * 8;
  char* AsB = (char*)Asl;
  char* BsB = (char*)Bsl;

  auto stage = [&](int k0, int buf) {
    __builtin_amdgcn_global_load_lds((GU32*)(Abase + k0),
                                     (LU32*)(AsB + buf * 8192 + tid * 16), 16, 0, 0);
    __builtin_amdgcn_global_load_lds((GU32*)(Abase + (size_t)64 * K + k0),
                                     (LU32*)(AsB + buf * 8192 + tid * 16 + 4096), 16, 0, 0);
    __builtin_amdgcn_global_load_lds((GU32*)(Bbase + k0),
                                     (LU32*)(BsB + buf * 8192 + tid * 16), 16, 0, 0);
    __builtin_amdgcn_global_load_lds((GU32*)(Bbase + (size_t)64 * K + k0),
                                     (LU32*)(BsB + buf * 8192 + tid * 16 + 4096), 16, 0, 0);
  };

  const int fr = lane & 15;
  const int fq = lane >> 4;
  const int rpos = (fq ^ ((fr >> 1) & 3)) * 8;

  floatx4 acc[4][4];
#pragma unroll
  for (int i = 0; i < 4; ++i)
#pragma unroll
    for (int j = 0; j < 4; ++j) acc[i][j] = (floatx4){0.f, 0.f, 0.f, 0.f};

  stage(0, 0);
  asm volatile("s_waitcnt vmcnt(0)" ::: "memory");
  __builtin_amdgcn_s_barrier();

  int cur = 0;
  for (int t = 0; t < NT; ++t) {
    if (t + 1 < NT) {
      stage((t + 1) * 32, cur ^ 1);
      asm volatile("s_waitcnt vmcnt(4)" ::: "memory");
    } else {
      asm volatile("s_waitcnt vmcnt(0)" ::: "memory");
    }
    __builtin_amdgcn_s_barrier();
    __builtin_amdgcn_sched_barrier(0);
    half8 af[4], bf[4];
#pragma unroll
    for (int f = 0; f < 4; ++f) {
      af[f] = *(const half8*)&Asl[cur][(wr * 64 + f * 16 + fr) * 32 + rpos];
      bf[f] = *(const half8*)&Bsl[cur][(wc * 64 + f * 16 + fr) * 32 + rpos];
    }
#pragma unroll
    for (int i = 0; i < 4; ++i)
#pragma unroll
      for (int j = 0; j < 4; ++j)
        acc[i][j] = __builtin_amdgcn_mfma_f32_16x16x32_f16(bf[j], af[i], acc[i][j], 0, 0, 0);
    __builtin_amdgcn_sched_barrier(0);
    __builtin_amdgcn_s_barrier();
    cur ^= 1;
  }

  // vector epilogue: lane -> C-row fr, C-cols fq*4 + j (contiguous)
  const int crow = wr * 64 + fr;
  const int ccol = wc * 64 + fq * 4;
#pragma unroll
  for (int fm = 0; fm < 4; ++fm) {
#pragma unroll
    for (int fn = 0; fn < 4; ++fn) {
      const size_t off = (row0 + crow + fm * 16) * (size_t)N + col0 + ccol + fn * 16;
      if (HALF_OUT) {
        _Float16* Cc = (_Float16*)Cout;
        half4 hv;
#pragma unroll
        for (int j = 0; j < 4; ++j) hv[j] = (_Float16)acc[fm][fn][j];
        *(half4*)(Cc + off) = hv;  // 8B store
      } else {
        float* Cc = (float*)Cout;
        const float4 bz = *(const float4*)&bias[col0 + ccol + fn * 16];
        float4 ov;
        ov.x = acc[fm][fn][0] + bz.x;
        ov.y = acc[fm][fn][1] + bz.y;
        ov.z = acc[fm][fn][2] + bz.z;
        ov.w = acc[fm][fn][3] + bz.w;
        *(float4*)(Cc + off) = ov;  // 16B store
      }
    }
  }
}

// ---------------- Local attention: one thread per (token, head), XCD-chunked ----------------
__global__ __launch_bounds__(256) void attn_kernel(const _Float16* __restrict__ qkv,
                                                   _Float16* __restrict__ y) {
  const int p = blockIdx.x;
  const int l = (p & 7) * (gridDim.x >> 3) + (p >> 3);
  const int idx = l * 256 + threadIdx.x;  // token*12 + head
  const int head = idx % 12;
  const int token = idx / 12;
  const int branch = head >> 2;
  const int dil = branch + 1;
  const int cbase = branch * 128 + (head & 3) * 32;
  const int xx = token % 56;
  const int yy = (token / 56) % 56;
  const int bimg = token / 3136;
  const float scale = 0.17677669529663687f;  // 1/sqrt(32)

  const _Float16* qp = qkv + (size_t)token * ROWQKV + cbase;
  half2v qh[16];
  *(half8*)&qh[0] = *(const half8*)(qp);
  *(half8*)&qh[4] = *(const half8*)(qp + 8);
  *(half8*)&qh[8] = *(const half8*)(qp + 16);
  *(half8*)&qh[12] = *(const half8*)(qp + 24);

  const size_t nbase = (size_t)bimg * 3136;

  float lg[9];
#pragma unroll
  for (int j = 0; j < 9; ++j) {
    const int ny = yy + (j / 3 - 1) * dil;
    const int nx = xx + (j % 3 - 1) * dil;
    float d = 0.f;
    if ((unsigned)ny < 56u && (unsigned)nx < 56u) {
      const _Float16* kp = qkv + (nbase + ny * 56 + nx) * ROWQKV + 384 + cbase;
      half2v kh[16];
      *(half8*)&kh[0] = *(const half8*)(kp);
      *(half8*)&kh[4] = *(const half8*)(kp + 8);
      *(half8*)&kh[8] = *(const half8*)(kp + 16);
      *(half8*)&kh[12] = *(const half8*)(kp + 24);
#if __has_builtin(__builtin_amdgcn_fdot2)
#pragma unroll
      for (int c = 0; c < 16; ++c) d = __builtin_amdgcn_fdot2(qh[c], kh[c], d, false);
#else
#pragma unroll
      for (int c = 0; c < 16; ++c)
        d += (float)qh[c][0] * (float)kh[c][0] + (float)qh[c][1] * (float)kh[c][1];
#endif
    }
    lg[j] = d * scale;
  }

  float m = lg[0];
#pragma unroll
  for (int j = 1; j < 9; ++j) m = fmaxf(m, lg[j]);
  float s = 0.f;
#pragma unroll
  for (int j = 0; j < 9; ++j) { lg[j] = expf(lg[j] - m); s += lg[j]; }
  const float rs = 1.f / s;

  float out[32];
#pragma unroll
  for (int c = 0; c < 32; ++c) out[c] = 0.f;
#pragma unroll
  for (int j = 0; j < 9; ++j) {
    const int ny = yy + (j / 3 - 1) * dil;
    const int nx = xx + (j % 3 - 1) * dil;
    if ((unsigned)ny < 56u && (unsigned)nx < 56u) {
      const _Float16* vp = qkv + (nbase + ny * 56 + nx) * ROWQKV + 768 + cbase;
      half8 vh[4];
      vh[0] = *(const half8*)(vp);
      vh[1] = *(const half8*)(vp + 8);
      vh[2] = *(const half8*)(vp + 16);
      vh[3] = *(const half8*)(vp + 24);
      const float pw = lg[j];
#pragma unroll
      for (int g = 0; g < 4; ++g)
#pragma unroll
        for (int e = 0; e < 8; ++e) out[g * 8 + e] = fmaf(pw, (float)vh[g][e], out[g * 8 + e]);
    }
  }

  _Float16* yp = y + (size_t)token * CDIM + cbase;
  half8 oh[4];
#pragma unroll
  for (int g = 0; g < 4; ++g) {
#pragma unroll
    for (int e = 0; e < 8; ++e) oh[g][e] = (_Float16)(out[g * 8 + e] * rs);
    *(half8*)(yp + g * 8) = oh[g];
  }
}

extern "C" void kernel_launch(void* const* d_in, const int* in_sizes, int n_in,
                              void* d_out, int out_size, void* d_ws, size_t ws_size,
                              hipStream_t stream) {
  const float* x = (const float*)d_in[0];       // [16,56,56,384]
  const float* w_qkv = (const float*)d_in[1];   // [1152,384]
  const float* w_proj = (const float*)d_in[2];  // [384,384]
  const float* b_proj = (const float*)d_in[3];  // [384]
  float* out = (float*)d_out;                   // [50176,384]

  _Float16* xh = (_Float16*)d_ws;                     // 50176*384
  _Float16* wqh = xh + (size_t)NTOK * CDIM;           // 1152*384
  _Float16* wph = wqh + (size_t)ROWQKV * CDIM;        // 384*384
  _Float16* qkvh = wph + (size_t)CDIM * CDIM;         // 50176*1152
  _Float16* yh = qkvh + (size_t)NTOK * ROWQKV;        // 50176*384

  conv_all<<<2048, 256, 0, stream>>>(x, w_qkv, w_proj, xh, wqh, wph);

  gemm3<true><<<(NTOK / 128) * (ROWQKV / 128), 256, 0, stream>>>(
      xh, wqh, nullptr, qkvh, ROWQKV, CDIM);

  attn_kernel<<<(NTOK * 12) / 256, 256, 0, stream>>>(qkvh, yh);

  gemm3<false><<<(NTOK / 128) * (CDIM / 128), 256, 0, stream>>>(
      yh, wph, b_proj, out, CDIM, CDIM);
}

// Round 18
// 184.462 us; speedup vs baseline: 2.1332x; 1.0694x over previous
//
#include <hip/hip_runtime.h>
#include <hip/hip_bf16.h>

// MultiDilatelocalAttention, round 18: round 13 exact (best, 178.5us) +
// s_setprio(1) around the attention compute sections (T5: catalog m191
// measured +4-7% on attn kernels with independent unsynced waves).
// GEMMs (2-buf counted-vmcnt, XCD remap) and conv_all unchanged from R13.

#define NTOK 50176
#define ROWQKV 1152
#define CDIM 384

typedef _Float16 half2v __attribute__((ext_vector_type(2)));
typedef _Float16 half8 __attribute__((ext_vector_type(8)));
typedef float floatx4 __attribute__((ext_vector_type(4)));

typedef __attribute__((address_space(1))) const unsigned int GU32;
typedef __attribute__((address_space(3))) unsigned int LU32;

// ---------------- fused fp32 -> fp16 conversion: x, w_qkv, w_proj ----------------
#define N_X4 (NTOK * CDIM / 4)
#define N_Q4 (ROWQKV * CDIM / 4)
#define N_P4 (CDIM * CDIM / 4)

__global__ __launch_bounds__(256) void conv_all(const float* __restrict__ x,
                                                const float* __restrict__ wq,
                                                const float* __restrict__ wp,
                                                _Float16* __restrict__ xh,
                                                _Float16* __restrict__ wqh,
                                                _Float16* __restrict__ wph) {
  const int total = N_X4 + N_Q4 + N_P4;
  int i = blockIdx.x * 256 + threadIdx.x;
  const int stride = gridDim.x * 256;
  for (; i < total; i += stride) {
    const float* src;
    _Float16* dst;
    int k;
    if (i < N_X4) { src = x; dst = xh; k = i; }
    else if (i < N_X4 + N_Q4) { src = wq; dst = wqh; k = i - N_X4; }
    else { src = wp; dst = wph; k = i - N_X4 - N_Q4; }
    float4 v = ((const float4*)src)[k];
    union { _Float16 h[4]; uint2 u; } o;
    o.h[0] = (_Float16)v.x; o.h[1] = (_Float16)v.y;
    o.h[2] = (_Float16)v.z; o.h[3] = (_Float16)v.w;
    ((uint2*)dst)[k] = o.u;
  }
}

// ---------------- f16 MFMA GEMM (round-8 exact): C = A * B^T, dbuf + vmcnt(4) ----------------
template <bool HALF_OUT>
__global__ __launch_bounds__(256) void gemm3(const _Float16* __restrict__ A,
                                             const _Float16* __restrict__ B,
                                             const float* __restrict__ bias,
                                             void* __restrict__ Cout,
                                             int N, int K) {
  __shared__ _Float16 Asl[2][128 * 32];
  __shared__ _Float16 Bsl[2][128 * 32];
  const int tid = threadIdx.x;
  const int lane = tid & 63;
  const int wv = tid >> 6;
  const int wr = wv >> 1, wc = wv & 1;

  const int nN = N >> 7;
  const int p = blockIdx.x;
  const int l = (p & 7) * (gridDim.x >> 3) + (p >> 3);
  const size_t row0 = (size_t)(l / nN) * 128;
  const int col0 = (l % nN) * 128;
  const int NT = K / 32;

  const int srow = tid >> 2;
  const int gslot = (tid & 3) ^ ((srow >> 1) & 3);
  const _Float16* Abase = A + (row0 + srow) * (size_t)K + gslot * 8;
  const _Float16* Bbase = B + ((size_t)(col0 + srow)) * (size_t)K + gslot * 8;
  char* AsB = (char*)Asl;
  char* BsB = (char*)Bsl;

  auto stage = [&](int k0, int buf) {
    __builtin_amdgcn_global_load_lds((GU32*)(Abase + k0),
                                     (LU32*)(AsB + buf * 8192 + tid * 16), 16, 0, 0);
    __builtin_amdgcn_global_load_lds((GU32*)(Abase + (size_t)64 * K + k0),
                                     (LU32*)(AsB + buf * 8192 + tid * 16 + 4096), 16, 0, 0);
    __builtin_amdgcn_global_load_lds((GU32*)(Bbase + k0),
                                     (LU32*)(BsB + buf * 8192 + tid * 16), 16, 0, 0);
    __builtin_amdgcn_global_load_lds((GU32*)(Bbase + (size_t)64 * K + k0),
                                     (LU32*)(BsB + buf * 8192 + tid * 16 + 4096), 16, 0, 0);
  };

  const int fr = lane & 15;
  const int fq = lane >> 4;
  const int rpos = (fq ^ ((fr >> 1) & 3)) * 8;

  floatx4 acc[4][4];
#pragma unroll
  for (int i = 0; i < 4; ++i)
#pragma unroll
    for (int j = 0; j < 4; ++j) acc[i][j] = (floatx4){0.f, 0.f, 0.f, 0.f};

  stage(0, 0);
  asm volatile("s_waitcnt vmcnt(0)" ::: "memory");
  __builtin_amdgcn_s_barrier();

  int cur = 0;
  for (int t = 0; t < NT; ++t) {
    if (t + 1 < NT) {
      stage((t + 1) * 32, cur ^ 1);
      asm volatile("s_waitcnt vmcnt(4)" ::: "memory");
    } else {
      asm volatile("s_waitcnt vmcnt(0)" ::: "memory");
    }
    __builtin_amdgcn_s_barrier();
    __builtin_amdgcn_sched_barrier(0);
    half8 af[4], bf[4];
#pragma unroll
    for (int f = 0; f < 4; ++f) {
      af[f] = *(const half8*)&Asl[cur][(wr * 64 + f * 16 + fr) * 32 + rpos];
      bf[f] = *(const half8*)&Bsl[cur][(wc * 64 + f * 16 + fr) * 32 + rpos];
    }
#pragma unroll
    for (int i = 0; i < 4; ++i)
#pragma unroll
      for (int j = 0; j < 4; ++j)
        acc[i][j] = __builtin_amdgcn_mfma_f32_16x16x32_f16(af[i], bf[j], acc[i][j], 0, 0, 0);
    __builtin_amdgcn_sched_barrier(0);
    __builtin_amdgcn_s_barrier();
    cur ^= 1;
  }

  const int crow = wr * 64 + (lane >> 4) * 4;
  const int ccol = wc * 64 + (lane & 15);
#pragma unroll
  for (int fm = 0; fm < 4; ++fm) {
#pragma unroll
    for (int fn = 0; fn < 4; ++fn) {
      const size_t r0 = (row0 + crow + fm * 16) * (size_t)N + col0 + ccol + fn * 16;
      if (HALF_OUT) {
        _Float16* Cc = (_Float16*)Cout;
#pragma unroll
        for (int j = 0; j < 4; ++j) Cc[r0 + (size_t)j * N] = (_Float16)acc[fm][fn][j];
      } else {
        float* Cc = (float*)Cout;
        const float bz = bias[col0 + ccol + fn * 16];
#pragma unroll
        for (int j = 0; j < 4; ++j) Cc[r0 + (size_t)j * N] = acc[fm][fn][j] + bz;
      }
    }
  }
}

// ---------------- Local attention: one thread per (token, head), XCD-chunked ----------------
__global__ __launch_bounds__(256) void attn_kernel(const _Float16* __restrict__ qkv,
                                                   _Float16* __restrict__ y) {
  const int p = blockIdx.x;
  const int l = (p & 7) * (gridDim.x >> 3) + (p >> 3);
  const int idx = l * 256 + threadIdx.x;  // token*12 + head
  const int head = idx % 12;
  const int token = idx / 12;
  const int branch = head >> 2;
  const int dil = branch + 1;
  const int cbase = branch * 128 + (head & 3) * 32;
  const int xx = token % 56;
  const int yy = (token / 56) % 56;
  const int bimg = token / 3136;
  const float scale = 0.17677669529663687f;  // 1/sqrt(32)

  const _Float16* qp = qkv + (size_t)token * ROWQKV + cbase;
  half2v qh[16];
  *(half8*)&qh[0] = *(const half8*)(qp);
  *(half8*)&qh[4] = *(const half8*)(qp + 8);
  *(half8*)&qh[8] = *(const half8*)(qp + 16);
  *(half8*)&qh[12] = *(const half8*)(qp + 24);

  const size_t nbase = (size_t)bimg * 3136;

  float lg[9];
#pragma unroll
  for (int j = 0; j < 9; ++j) {
    const int ny = yy + (j / 3 - 1) * dil;
    const int nx = xx + (j % 3 - 1) * dil;
    float d = 0.f;
    if ((unsigned)ny < 56u && (unsigned)nx < 56u) {
      const _Float16* kp = qkv + (nbase + ny * 56 + nx) * ROWQKV + 384 + cbase;
      half2v kh[16];
      *(half8*)&kh[0] = *(const half8*)(kp);
      *(half8*)&kh[4] = *(const half8*)(kp + 8);
      *(half8*)&kh[8] = *(const half8*)(kp + 16);
      *(half8*)&kh[12] = *(const half8*)(kp + 24);
      __builtin_amdgcn_s_setprio(1);   // prioritize compute over other waves' load-issue
#if __has_builtin(__builtin_amdgcn_fdot2)
#pragma unroll
      for (int c = 0; c < 16; ++c) d = __builtin_amdgcn_fdot2(qh[c], kh[c], d, false);
#else
#pragma unroll
      for (int c = 0; c < 16; ++c)
        d += (float)qh[c][0] * (float)kh[c][0] + (float)qh[c][1] * (float)kh[c][1];
#endif
      __builtin_amdgcn_s_setprio(0);
    }
    lg[j] = d * scale;
  }

  __builtin_amdgcn_s_setprio(1);
  float m = lg[0];
#pragma unroll
  for (int j = 1; j < 9; ++j) m = fmaxf(m, lg[j]);
  float s = 0.f;
#pragma unroll
  for (int j = 0; j < 9; ++j) { lg[j] = expf(lg[j] - m); s += lg[j]; }
  const float rs = 1.f / s;
  __builtin_amdgcn_s_setprio(0);

  float out[32];
#pragma unroll
  for (int c = 0; c < 32; ++c) out[c] = 0.f;
#pragma unroll
  for (int j = 0; j < 9; ++j) {
    const int ny = yy + (j / 3 - 1) * dil;
    const int nx = xx + (j % 3 - 1) * dil;
    if ((unsigned)ny < 56u && (unsigned)nx < 56u) {
      const _Float16* vp = qkv + (nbase + ny * 56 + nx) * ROWQKV + 768 + cbase;
      half8 vh[4];
      vh[0] = *(const half8*)(vp);
      vh[1] = *(const half8*)(vp + 8);
      vh[2] = *(const half8*)(vp + 16);
      vh[3] = *(const half8*)(vp + 24);
      const float pw = lg[j];
      __builtin_amdgcn_s_setprio(1);
#pragma unroll
      for (int g = 0; g < 4; ++g)
#pragma unroll
        for (int e = 0; e < 8; ++e) out[g * 8 + e] = fmaf(pw, (float)vh[g][e], out[g * 8 + e]);
      __builtin_amdgcn_s_setprio(0);
    }
  }

  _Float16* yp = y + (size_t)token * CDIM + cbase;
  half8 oh[4];
#pragma unroll
  for (int g = 0; g < 4; ++g) {
#pragma unroll
    for (int e = 0; e < 8; ++e) oh[g][e] = (_Float16)(out[g * 8 + e] * rs);
    *(half8*)(yp + g * 8) = oh[g];
  }
}

extern "C" void kernel_launch(void* const* d_in, const int* in_sizes, int n_in,
                              void* d_out, int out_size, void* d_ws, size_t ws_size,
                              hipStream_t stream) {
  const float* x = (const float*)d_in[0];       // [16,56,56,384]
  const float* w_qkv = (const float*)d_in[1];   // [1152,384]
  const float* w_proj = (const float*)d_in[2];  // [384,384]
  const float* b_proj = (const float*)d_in[3];  // [384]
  float* out = (float*)d_out;                   // [50176,384]

  _Float16* xh = (_Float16*)d_ws;                     // 50176*384
  _Float16* wqh = xh + (size_t)NTOK * CDIM;           // 1152*384
  _Float16* wph = wqh + (size_t)ROWQKV * CDIM;        // 384*384
  _Float16* qkvh = wph + (size_t)CDIM * CDIM;         // 50176*1152
  _Float16* yh = qkvh + (size_t)NTOK * ROWQKV;        // 50176*384

  conv_all<<<2048, 256, 0, stream>>>(x, w_qkv, w_proj, xh, wqh, wph);

  gemm3<true><<<(NTOK / 128) * (ROWQKV / 128), 256, 0, stream>>>(
      xh, wqh, nullptr, qkvh, ROWQKV, CDIM);

  attn_kernel<<<(NTOK * 12) / 256, 256, 0, stream>>>(qkvh, yh);

  gemm3<false><<<(NTOK / 128) * (CDIM / 128), 256, 0, stream>>>(
      yh, wph, b_proj, out, CDIM, CDIM);
}